// Round 13
// baseline (211.550 us; speedup 1.0000x reference)
//
#include <hip/hip_runtime.h>
#include <math.h>
#include <stdint.h>

// Problem constants (fixed by setup_inputs)
constexpr int K_ = 4, B_ = 8, T_ = 800, C_ = 80, S_ = 128, Z_ = 32;
constexpr int KB_ = K_ * B_;        // 32
constexpr int TC_ = T_ * C_;        // 64000

#define BIGV   1e8f
#define GHOSTH 65504.0f             // fp16 max: ghost-cell D (real cells ~5-20K)
#define WARP_V 256.0f

// R25 = R24 (fp16 g=8 sheared stream, verified absmax 0) with 4->2 kernel
// consolidation: ghost-fill runs inside gemm (designated block per kb);
// finalize runs inside the LAST dtw block (device-scope counter pattern).
constexpr int NU_   = 900;            // u = j + (i>>3) <= 799 + 99 = 898
constexpr int SLAB_ = NU_ * 800;      // 720,000 halves per problem (46 MB total)

__device__ __forceinline__ float sigmoidf_(float v) {
    return 1.f / (1.f + __expf(-v));
}

// ---------------------------------------------------------------- banded GEMM -> sheared Q (norms fused)
// R20 single-stage structure; fp16 stores; fused: cnt reset + ghost fill.
__global__ __launch_bounds__(256) void gemm_band(const float* __restrict__ mel_iters,
                                                 const float* __restrict__ mel_targets,
                                                 _Float16* __restrict__ Dm,
                                                 int* __restrict__ cnt) {
    const int kb = blockIdx.z;
    const int b  = kb & 7;
    const int ti = blockIdx.y;
    const int tj = ti + (int)blockIdx.x - 2;
    const int tid = threadIdx.x;

    // reset the dtw completion counter once per launch (before band check!)
    if (blockIdx.x == 0 && blockIdx.y == 0 && blockIdx.z == 0 && tid == 0) *cnt = 0;

    if ((unsigned)tj > 12u) return;

    // ghost cells j = -1 (lanes l<=11 read Q[2l][16l+8..15] at their 1st step):
    // one designated active block per kb writes them.
    if (blockIdx.x == 2 && ti == 0 && tid < 184) {
        int i = 8 + tid;     // i in [8, 191]
        Dm[(size_t)kb * SLAB_ + (size_t)((i >> 3) - 1) * 800 + i] = (_Float16)GHOSTH;
    }

    const float* __restrict__ Xb = mel_iters + (size_t)kb * TC_;
    const float* __restrict__ Yb = mel_targets + (size_t)b * TC_;

    __shared__ float smem[10880];            // xa[80][68] | ya[80][68]; phase2: Zt[71][65]
    __shared__ float x2s[64], y2s[64];
    float (*xa)[68] = (float(*)[68])smem;
    float (*ya)[68] = (float(*)[68])(smem + 5440);

    const int tx = tid & 15, ty = tid >> 4;
    const int i0 = ti * 64, j0 = tj * 64;

    // ---- single-stage: sigmoid(X) 64x80 and sigmoid(Y) 64x80 into LDS
    {
        const int row = tid & 63, seg = tid >> 6;      // 4 threads per row
        const int gi = min(i0 + row, T_ - 1);
        const int gj = min(j0 + row, T_ - 1);
        const float4* Xr = (const float4*)(Xb + (size_t)gi * C_);
        const float4* Yr = (const float4*)(Yb + (size_t)gj * C_);
        #pragma unroll
        for (int m = 0; m < 5; ++m) {
            const int k4 = seg * 5 + m;
            float4 xv = Xr[k4], yv = Yr[k4];
            const int k = k4 * 4;
            xa[k + 0][row] = sigmoidf_(xv.x); xa[k + 1][row] = sigmoidf_(xv.y);
            xa[k + 2][row] = sigmoidf_(xv.z); xa[k + 3][row] = sigmoidf_(xv.w);
            ya[k + 0][row] = sigmoidf_(yv.x); ya[k + 1][row] = sigmoidf_(yv.y);
            ya[k + 2][row] = sigmoidf_(yv.z); ya[k + 3][row] = sigmoidf_(yv.w);
        }
    }
    __syncthreads();

    // ---- row norms, k ascending
    if (tid < 64) {
        float s = 0.f;
        for (int k = 0; k < C_; ++k) { float v = xa[k][tid]; s += v * v; }
        x2s[tid] = s;
    } else if (tid < 128) {
        float s = 0.f;
        for (int k = 0; k < C_; ++k) { float v = ya[k][tid - 64]; s += v * v; }
        y2s[tid - 64] = s;
    }

    // ---- 80-deep FMA
    float acc[4][4] = {};
    #pragma unroll 16
    for (int k = 0; k < C_; ++k) {
        float4 av = *(const float4*)&xa[k][ty * 4];
        float4 bv = *(const float4*)&ya[k][tx * 4];
        acc[0][0] += av.x * bv.x; acc[0][1] += av.x * bv.y; acc[0][2] += av.x * bv.z; acc[0][3] += av.x * bv.w;
        acc[1][0] += av.y * bv.x; acc[1][1] += av.y * bv.y; acc[1][2] += av.y * bv.z; acc[1][3] += av.y * bv.w;
        acc[2][0] += av.z * bv.x; acc[2][1] += av.z * bv.y; acc[2][2] += av.z * bv.z; acc[2][3] += av.z * bv.w;
        acc[3][0] += av.w * bv.x; acc[3][1] += av.w * bv.y; acc[3][2] += av.w * bv.z; acc[3][3] += av.w * bv.w;
    }
    __syncthreads();

    float xs2[4], ys2[4];
    #pragma unroll
    for (int r = 0; r < 4; ++r) xs2[r] = x2s[ty * 4 + r];
    #pragma unroll
    for (int c = 0; c < 4; ++c) ys2[c] = y2s[tx * 4 + c];

    // sheared LDS tile (g=8): Zt[u_rel][iLoc], u_rel = 4tx + c + (ty>>1)
    float* Zt = smem;                     // [71][65]
    const int sb = ty >> 1;
    #pragma unroll
    for (int r = 0; r < 4; ++r)
        #pragma unroll
        for (int c = 0; c < 4; ++c)
            Zt[(4 * tx + c + sb) * 65 + (4 * ty + r)] = xs2[r] + ys2[c] - 2.f * acc[r][c];
    __syncthreads();

    // coalesced u-row stores (fp16): u_global = j0 + 8ti + w
    const int w0 = tid >> 6;              // wave id 0..3
    const int lane = tid & 63;
    const int iGlob = i0 + lane;
    const int sbl = lane >> 3;            // (i>>3) - 8ti
    const bool iok = iGlob < T_;
    const size_t ub = (size_t)(j0 + 8 * ti) * 800 + iGlob;
    #pragma unroll
    for (int it = 0; it < 18; ++it) {
        int w = w0 + it * 4;
        if (w > 70) break;
        int jrel = w - sbl;
        if (iok && (unsigned)jrel < 64u && (j0 + jrel) < T_)
            Dm[(size_t)kb * SLAB_ + ub + (size_t)w * 800] = (_Float16)Zt[w * 65 + lane];
    }
}

// ---------------------------------------------------------------- single-wave hard-min DTW, fp16 stream
// R24 DP dataflow (verified); fused finalize in the last-completing block.
// Register map:
//   v42 = BIG  v43,v44 = temps  v45 = tinE  v46 = tinWE  v47 = tinO  v48 = tinWO
//   sE = v50-65  wE = v66-81  sO = v82-97  wO = v98-113
//   ring: 8 slots x 8 dwords (16 halves = 1 step) = v114-v177,
//   16 loads in flight, wait vmcnt(14).

#define DCELL2(aS,aA,aB,aC,aQ,aH,aW, bS,bA,bB,bC,bQ,bH,bW) \
  "v_min3_f32 v" #aS ", v" #aA ", v" #aB ", v" #aC "\n\t" \
  "v_min3_f32 v" #bS ", v" #bA ", v" #bB ", v" #bC "\n\t" \
  "v_fma_mix_f32 v" #aS ", v" #aQ ", 1.0, v" #aS " op_sel:[" #aH ",0,0] op_sel_hi:[1,0,0]\n\t" \
  "v_fma_mix_f32 v" #bS ", v" #bQ ", 1.0, v" #bS " op_sel:[" #bH ",0,0] op_sel_hi:[1,0,0]\n\t" \
  "v_add_f32 v" #aW ", %[wK], v" #aS "\n\t" \
  "v_add_f32 v" #bW ", %[wK], v" #bS "\n\t"

// STEP_E: reads sE/wE (+tinE,tinWO), writes sO/wO. Dword Qk holds halves 2k,2k+1.
#define STEP_E(Q0,Q1,Q2,Q3,Q4,Q5,Q6,Q7) \
  DCELL2(82, 45, 48, 66, Q0,0, 98,    90, 89, 73, 74, Q4,0, 106) \
  DCELL2(83, 50, 98, 67, Q0,1, 99,    91, 58, 106, 75, Q4,1, 107) \
  DCELL2(84, 51, 99, 68, Q1,0, 100,   92, 59, 107, 76, Q5,0, 108) \
  DCELL2(85, 52, 100, 69, Q1,1, 101,  93, 60, 108, 77, Q5,1, 109) \
  DCELL2(86, 53, 101, 70, Q2,0, 102,  94, 61, 109, 78, Q6,0, 110) \
  DCELL2(87, 54, 102, 71, Q2,1, 103,  95, 62, 110, 79, Q6,1, 111) \
  DCELL2(88, 55, 103, 72, Q3,0, 104,  96, 63, 111, 80, Q7,0, 112) \
  DCELL2(89, 56, 104, 73, Q3,1, 105,  97, 64, 112, 81, Q7,1, 113)

#define STEP_O(Q0,Q1,Q2,Q3,Q4,Q5,Q6,Q7) \
  DCELL2(50, 47, 46, 98, Q0,0, 66,    58, 57, 105, 106, Q4,0, 74) \
  DCELL2(51, 82, 66, 99, Q0,1, 67,    59, 90, 74, 107, Q4,1, 75) \
  DCELL2(52, 83, 67, 100, Q1,0, 68,   60, 91, 75, 108, Q5,0, 76) \
  DCELL2(53, 84, 68, 101, Q1,1, 69,   61, 92, 76, 109, Q5,1, 77) \
  DCELL2(54, 85, 69, 102, Q2,0, 70,   62, 93, 77, 110, Q6,0, 78) \
  DCELL2(55, 86, 70, 103, Q2,1, 71,   63, 94, 78, 111, Q6,1, 79) \
  DCELL2(56, 87, 71, 104, Q3,0, 72,   64, 95, 79, 112, Q7,0, 80) \
  DCELL2(57, 88, 72, 105, Q3,1, 73,   65, 96, 80, 113, Q7,1, 81)

#define HO_E \
  "s_nop 1\n\t" \
  "v_mov_b32_dpp v43, v97 wave_shr:1 row_mask:0xf bank_mask:0xf bound_ctrl:0\n\t" \
  "v_cndmask_b32 v45, v43, v42, %[msk]\n\t" \
  "v_add_f32 v46, %[wK], v45\n\t"

#define HO_O \
  "s_nop 1\n\t" \
  "v_mov_b32_dpp v43, v65 wave_shr:1 row_mask:0xf bank_mask:0xf bound_ctrl:0\n\t" \
  "v_cndmask_b32 v47, v43, v42, %[msk]\n\t" \
  "v_add_f32 v48, %[wK], v47\n\t"

#define PREF(r0,r1,K) \
  "s_add_u32 %[st], %[su], " #K "\n\t" \
  "v_med3_i32 v43, %[st], %[vlo], %[vhi]\n\t" \
  "v_mad_u32_u24 v44, v43, %[c32], %[vl4]\n\t" \
  "global_load_dwordx4 " r0 ", v44, %[bp]\n\t" \
  "global_load_dwordx4 " r1 ", v44, %[bp] offset:16\n\t"

#define PREF0(K) PREF("v[114:117]","v[118:121]",K)
#define PREF1(K) PREF("v[122:125]","v[126:129]",K)
#define PREF2(K) PREF("v[130:133]","v[134:137]",K)
#define PREF3(K) PREF("v[138:141]","v[142:145]",K)
#define PREF4(K) PREF("v[146:149]","v[150:153]",K)
#define PREF5(K) PREF("v[154:157]","v[158:161]",K)
#define PREF6(K) PREF("v[162:165]","v[166:169]",K)
#define PREF7(K) PREF("v[170:173]","v[174:177]",K)

#define SLOT0 (114,115,116,117,118,119,120,121)
#define SLOT1 (122,123,124,125,126,127,128,129)
#define SLOT2 (130,131,132,133,134,135,136,137)
#define SLOT3 (138,139,140,141,142,143,144,145)
#define SLOT4 (146,147,148,149,150,151,152,153)
#define SLOT5 (154,155,156,157,158,159,160,161)
#define SLOT6 (162,163,164,165,166,167,168,169)
#define SLOT7 (170,171,172,173,174,175,176,177)

// Indirection so `M` is rescanned adjacent to the prescan-expanded paren list.
#define DTW_CALL(M, A) M A

#define MV(n) "v_mov_b32 v" #n ", v42\n\t"
#define W14 "s_waitcnt vmcnt(14)\n\t"

__global__ __launch_bounds__(64)
void dtw_wave_kernel(const _Float16* __restrict__ Dm, float* __restrict__ dtwv,
                     int* __restrict__ cnt,
                     const int* __restrict__ mel_lens, const int* __restrict__ src_lens,
                     const float* __restrict__ durations, const float* __restrict__ mus,
                     const float* __restrict__ log_vars, const int* __restrict__ step,
                     float* __restrict__ out) {
    const int kb = blockIdx.x;
    const int l  = threadIdx.x;
    const int lc = l < 49 ? l : 49;             // lanes 50-63 mirror lane 49
    const _Float16* __restrict__ Dd = Dm + (size_t)kb * SLAB_;

    const int ti_l = lc >> 2;
    const int Jlo = ti_l >= 2 ? 64 * (ti_l - 2) : 0;
    const int Jhi = min(799, 64 * ti_l + 191);
    const int lo_u = (Jlo == 0) ? (2 * lc) : (Jlo + 2 * lc + 1);
    const int hi_u = Jhi + 2 * lc + 1;
    const unsigned lofs = (unsigned)(lc << 5);      // 32 B per lane within row

    float res;
    unsigned su_d, st_d;

    asm volatile(
        // ---- init constants & state
        "v_mov_b32 v42, %[vbig]\n\t"
        MV(50) MV(51) MV(52) MV(53) MV(54) MV(55) MV(56) MV(57)
        MV(58) MV(59) MV(60) MV(61) MV(62) MV(63) MV(64) MV(65)
        MV(66) MV(67) MV(68) MV(69) MV(70) MV(71) MV(72) MV(73)
        MV(74) MV(75) MV(76) MV(77) MV(78) MV(79) MV(80) MV(81)
        MV(82) MV(83) MV(84) MV(85) MV(86) MV(87) MV(88) MV(89)
        MV(90) MV(91) MV(92) MV(93) MV(94) MV(95) MV(96) MV(97)
        MV(98) MV(99) MV(100) MV(101) MV(102) MV(103) MV(104) MV(105)
        MV(106) MV(107) MV(108) MV(109) MV(110) MV(111) MV(112) MV(113)
        "v_cndmask_b32 v45, v42, 0, %[msk]\n\t"   // tinE: lane0 -> 0, else BIG
        "v_mov_b32 v46, v42\n\t"                  // tinWE
        "v_mov_b32 v47, v42\n\t"                  // tinO
        "v_mov_b32 v48, v42\n\t"                  // tinWO (read at step 0: BIG)
        "s_mov_b32 %[su], 0\n\t"
        // ---- prefill 8 slots (u = 0..7), 16 loads in flight
        PREF0(0) PREF1(1) PREF2(2) PREF3(3) PREF4(4) PREF5(5) PREF6(6) PREF7(7)
        // ---- main loop: 111 iters x 8 steps = steps 0..887
        "1:\n\t"
        W14 DTW_CALL(STEP_E, SLOT0) HO_E PREF0(8)
        W14 DTW_CALL(STEP_O, SLOT1) HO_O PREF1(9)
        W14 DTW_CALL(STEP_E, SLOT2) HO_E PREF2(10)
        W14 DTW_CALL(STEP_O, SLOT3) HO_O PREF3(11)
        W14 DTW_CALL(STEP_E, SLOT4) HO_E PREF4(12)
        W14 DTW_CALL(STEP_O, SLOT5) HO_O PREF5(13)
        W14 DTW_CALL(STEP_E, SLOT6) HO_E PREF6(14)
        W14 DTW_CALL(STEP_O, SLOT7) HO_O PREF7(15)
        "s_add_u32 %[su], %[su], 8\n\t"
        "s_cmp_lg_u32 %[su], 888\n\t"
        "s_cbranch_scc1 1b\n\t"
        // ---- tail: steps 888..898 (su = 888)
        W14 DTW_CALL(STEP_E, SLOT0) HO_E PREF0(8)            // 888, refill 896
        W14 DTW_CALL(STEP_O, SLOT1) HO_O PREF1(9)            // 889, refill 897
        W14 DTW_CALL(STEP_E, SLOT2) HO_E PREF2(10)           // 890, refill 898
        W14 DTW_CALL(STEP_O, SLOT3) HO_O                     // 891
        "s_waitcnt vmcnt(12)\n\t" DTW_CALL(STEP_E, SLOT4) HO_E   // 892
        "s_waitcnt vmcnt(10)\n\t" DTW_CALL(STEP_O, SLOT5) HO_O   // 893
        "s_waitcnt vmcnt(8)\n\t"  DTW_CALL(STEP_E, SLOT6) HO_E   // 894
        "s_waitcnt vmcnt(6)\n\t"  DTW_CALL(STEP_O, SLOT7) HO_O   // 895
        "s_waitcnt vmcnt(4)\n\t"  DTW_CALL(STEP_E, SLOT0) HO_E   // 896
        "s_waitcnt vmcnt(2)\n\t"  DTW_CALL(STEP_O, SLOT1) HO_O   // 897
        "s_waitcnt vmcnt(0)\n\t"  DTW_CALL(STEP_E, SLOT2)        // 898
        "v_mov_b32 %[res], v97\n\t"
        : [res] "=v"(res), [su] "=&s"(su_d), [st] "=&s"(st_d)
        : [vlo] "v"(lo_u), [vhi] "v"(hi_u), [vl4] "v"(lofs),
          [vbig] "v"(BIGV), [wK] "s"(WARP_V), [c32] "s"(1600u),
          [msk] "s"(1ull), [bp] "s"((const void*)Dd)
        : "memory", "scc",
          "v42","v43","v44","v45","v46","v47","v48","v49",
          "v50","v51","v52","v53","v54","v55","v56","v57","v58","v59",
          "v60","v61","v62","v63","v64","v65","v66","v67","v68","v69",
          "v70","v71","v72","v73","v74","v75","v76","v77","v78","v79",
          "v80","v81","v82","v83","v84","v85","v86","v87","v88","v89",
          "v90","v91","v92","v93","v94","v95","v96","v97","v98","v99",
          "v100","v101","v102","v103","v104","v105","v106","v107","v108","v109",
          "v110","v111","v112","v113","v114","v115","v116","v117","v118","v119",
          "v120","v121","v122","v123","v124","v125","v126","v127","v128","v129",
          "v130","v131","v132","v133","v134","v135","v136","v137","v138","v139",
          "v140","v141","v142","v143","v144","v145","v146","v147","v148","v149",
          "v150","v151","v152","v153","v154","v155","v156","v157","v158","v159",
          "v160","v161","v162","v163","v164","v165","v166","v167","v168","v169",
          "v170","v171","v172","v173","v174","v175","v176","v177"
    );

    if (l == 49) dtwv[kb] = res;

    // ---- fused finalize: last block to finish does the scalar epilogue
    __threadfence();                                    // release dtwv[kb]
    unsigned old = 0;
    if (l == 0)
        old = (unsigned)__hip_atomic_fetch_add(cnt, 1, __ATOMIC_ACQ_REL,
                                               __HIP_MEMORY_SCOPE_AGENT);
    old = __shfl(old, 0);
    if (old == (unsigned)(KB_ - 1)) {
        __threadfence();                                // acquire others' dtwv
        const int lane = l;

        float v = (lane < KB_) ? dtwv[lane] : 0.f;
        for (int o = 32; o; o >>= 1) v += __shfl_down(v, o);

        float w = (lane < B_) ? 1.f / (K_ * (float)mel_lens[lane]) : 0.f;
        for (int o = 32; o; o >>= 1) w += __shfl_down(w, o);

        float du = 0.f;
        if (lane < B_) {
            float s = 0.f;
            for (int j = 0; j < S_; ++j) s += durations[lane * S_ + j];
            du = fabsf(s - (float)mel_lens[lane]) / (float)src_lens[lane];
        }
        for (int o = 32; o; o >>= 1) du += __shfl_down(du, o);

        float kl = 0.f;
        for (int j = lane; j < B_ * Z_; j += 64) {
            float muv = mus[j], lv = log_vars[j];
            kl += 1.f + lv - muv * muv - expf(lv);
        }
        for (int o = 32; o; o >>= 1) kl += __shfl_down(kl, o);

        if (lane == 0) {
            float mel_iter_loss = v / (float)B_;
            float mel_loss = mel_iter_loss * (w / (float)B_);
            float dur_loss = 2.0f * du / (float)B_;
            float kl_loss = -0.5f * kl;
            int st = step[0];
            float beta = (st < 2000) ? 0.f : ((st >= 8000) ? 1.f : (float)(st - 2000) / 6000.f);
            out[0] = mel_loss + dur_loss + beta * kl_loss;
            out[1] = mel_loss;
            out[2] = dur_loss;
            out[3] = kl_loss;
            out[4] = beta;
        }
    }
}

// ---------------------------------------------------------------- launch
extern "C" void kernel_launch(void* const* d_in, const int* in_sizes, int n_in,
                              void* d_out, int out_size, void* d_ws, size_t ws_size,
                              hipStream_t stream) {
    const float* mel_iters   = (const float*)d_in[0];
    const float* mel_targets = (const float*)d_in[1];
    const int*   mel_lens    = (const int*)d_in[2];
    const int*   src_lens    = (const int*)d_in[3];
    const float* durations   = (const float*)d_in[4];
    const float* mus         = (const float*)d_in[5];
    const float* log_vars    = (const float*)d_in[6];
    const int*   step        = (const int*)d_in[7];
    float* out = (float*)d_out;

    _Float16* Dm = (_Float16*)d_ws;                               // 32 * 720,000 halves = 46 MB
    char* tail   = (char*)d_ws + (size_t)KB_ * SLAB_ * sizeof(_Float16);
    float* dtwv  = (float*)tail;                                  // 32 floats
    int*   cnt   = (int*)(tail + 32 * sizeof(float));             // 1 int

    gemm_band<<<dim3(5, 13, KB_), 256, 0, stream>>>(mel_iters, mel_targets, Dm, cnt);

    dtw_wave_kernel<<<KB_, 64, 0, stream>>>(Dm, dtwv, cnt, mel_lens, src_lens,
                                            durations, mus, log_vars, step, out);
}

// Round 14
// 209.017 us; speedup vs baseline: 1.0121x; 1.0121x over previous
//
#include <hip/hip_runtime.h>
#include <math.h>
#include <stdint.h>

// Problem constants (fixed by setup_inputs)
constexpr int K_ = 4, B_ = 8, T_ = 800, C_ = 80, S_ = 128, Z_ = 32;
constexpr int KB_ = K_ * B_;        // 32
constexpr int TC_ = T_ * C_;        // 64000

#define BIGV   1e8f
#define GHOSTH 65504.0f             // fp16 max: ghost-cell D (real cells ~5-20K)
#define WARP_V 256.0f

// R26 = R24 fp16 g=8 sheared stream (verified absmax 0), 3-node graph:
//   gemm (+fused ghost-fill) -> dtw (clean R24) -> finalize.
// R13's lesson: in-kernel __threadfence (device release) costs ~7us on
// gfx950 (L2 writeback on non-coherent XCD L2s) -- more than a node. Keep
// kernel boundaries for cross-kernel visibility; fuse only fence-free work.
constexpr int NU_   = 900;            // u = j + (i>>3) <= 799 + 99 = 898
constexpr int SLAB_ = NU_ * 800;      // 720,000 halves per problem (46 MB total)

__device__ __forceinline__ float sigmoidf_(float v) {
    return 1.f / (1.f + __expf(-v));
}

// ---------------------------------------------------------------- banded GEMM -> sheared Q (norms fused)
// R20 single-stage structure; fp16 stores; fused ghost fill (j = -1 cells).
__global__ __launch_bounds__(256) void gemm_band(const float* __restrict__ mel_iters,
                                                 const float* __restrict__ mel_targets,
                                                 _Float16* __restrict__ Dm) {
    const int kb = blockIdx.z;
    const int b  = kb & 7;
    const int ti = blockIdx.y;
    const int tj = ti + (int)blockIdx.x - 2;
    const int tid = threadIdx.x;

    if ((unsigned)tj > 12u) return;

    // ghost cells j = -1 (lanes l<=11 read Q[2l][16l+8..15] at their 1st step):
    // one designated active block per kb writes them. gemm itself never
    // writes jrel<0 cells, so there is no same-kernel ordering hazard.
    if (blockIdx.x == 2 && ti == 0 && tid < 184) {
        int i = 8 + tid;     // i in [8, 191]
        Dm[(size_t)kb * SLAB_ + (size_t)((i >> 3) - 1) * 800 + i] = (_Float16)GHOSTH;
    }

    const float* __restrict__ Xb = mel_iters + (size_t)kb * TC_;
    const float* __restrict__ Yb = mel_targets + (size_t)b * TC_;

    __shared__ float smem[10880];            // xa[80][68] | ya[80][68]; phase2: Zt[71][65]
    __shared__ float x2s[64], y2s[64];
    float (*xa)[68] = (float(*)[68])smem;
    float (*ya)[68] = (float(*)[68])(smem + 5440);

    const int tx = tid & 15, ty = tid >> 4;
    const int i0 = ti * 64, j0 = tj * 64;

    // ---- single-stage: sigmoid(X) 64x80 and sigmoid(Y) 64x80 into LDS
    {
        const int row = tid & 63, seg = tid >> 6;      // 4 threads per row
        const int gi = min(i0 + row, T_ - 1);
        const int gj = min(j0 + row, T_ - 1);
        const float4* Xr = (const float4*)(Xb + (size_t)gi * C_);
        const float4* Yr = (const float4*)(Yb + (size_t)gj * C_);
        #pragma unroll
        for (int m = 0; m < 5; ++m) {
            const int k4 = seg * 5 + m;
            float4 xv = Xr[k4], yv = Yr[k4];
            const int k = k4 * 4;
            xa[k + 0][row] = sigmoidf_(xv.x); xa[k + 1][row] = sigmoidf_(xv.y);
            xa[k + 2][row] = sigmoidf_(xv.z); xa[k + 3][row] = sigmoidf_(xv.w);
            ya[k + 0][row] = sigmoidf_(yv.x); ya[k + 1][row] = sigmoidf_(yv.y);
            ya[k + 2][row] = sigmoidf_(yv.z); ya[k + 3][row] = sigmoidf_(yv.w);
        }
    }
    __syncthreads();

    // ---- row norms, k ascending
    if (tid < 64) {
        float s = 0.f;
        for (int k = 0; k < C_; ++k) { float v = xa[k][tid]; s += v * v; }
        x2s[tid] = s;
    } else if (tid < 128) {
        float s = 0.f;
        for (int k = 0; k < C_; ++k) { float v = ya[k][tid - 64]; s += v * v; }
        y2s[tid - 64] = s;
    }

    // ---- 80-deep FMA
    float acc[4][4] = {};
    #pragma unroll 16
    for (int k = 0; k < C_; ++k) {
        float4 av = *(const float4*)&xa[k][ty * 4];
        float4 bv = *(const float4*)&ya[k][tx * 4];
        acc[0][0] += av.x * bv.x; acc[0][1] += av.x * bv.y; acc[0][2] += av.x * bv.z; acc[0][3] += av.x * bv.w;
        acc[1][0] += av.y * bv.x; acc[1][1] += av.y * bv.y; acc[1][2] += av.y * bv.z; acc[1][3] += av.y * bv.w;
        acc[2][0] += av.z * bv.x; acc[2][1] += av.z * bv.y; acc[2][2] += av.z * bv.z; acc[2][3] += av.z * bv.w;
        acc[3][0] += av.w * bv.x; acc[3][1] += av.w * bv.y; acc[3][2] += av.w * bv.z; acc[3][3] += av.w * bv.w;
    }
    __syncthreads();

    float xs2[4], ys2[4];
    #pragma unroll
    for (int r = 0; r < 4; ++r) xs2[r] = x2s[ty * 4 + r];
    #pragma unroll
    for (int c = 0; c < 4; ++c) ys2[c] = y2s[tx * 4 + c];

    // sheared LDS tile (g=8): Zt[u_rel][iLoc], u_rel = 4tx + c + (ty>>1)
    float* Zt = smem;                     // [71][65]
    const int sb = ty >> 1;
    #pragma unroll
    for (int r = 0; r < 4; ++r)
        #pragma unroll
        for (int c = 0; c < 4; ++c)
            Zt[(4 * tx + c + sb) * 65 + (4 * ty + r)] = xs2[r] + ys2[c] - 2.f * acc[r][c];
    __syncthreads();

    // coalesced u-row stores (fp16): u_global = j0 + 8ti + w
    const int w0 = tid >> 6;              // wave id 0..3
    const int lane = tid & 63;
    const int iGlob = i0 + lane;
    const int sbl = lane >> 3;            // (i>>3) - 8ti
    const bool iok = iGlob < T_;
    const size_t ub = (size_t)(j0 + 8 * ti) * 800 + iGlob;
    #pragma unroll
    for (int it = 0; it < 18; ++it) {
        int w = w0 + it * 4;
        if (w > 70) break;
        int jrel = w - sbl;
        if (iok && (unsigned)jrel < 64u && (j0 + jrel) < T_)
            Dm[(size_t)kb * SLAB_ + ub + (size_t)w * 800] = (_Float16)Zt[w * 65 + lane];
    }
}

// ---------------------------------------------------------------- single-wave hard-min DTW, fp16 stream
// R26 = exact R24 (best measured: 96.4us, absmax 0). DP dataflow from R18;
// D consumed as f16 via v_fma_mix_f32. Register map:
//   v42 = BIG  v43,v44 = temps  v45 = tinE  v46 = tinWE  v47 = tinO  v48 = tinWO
//   sE = v50-65  wE = v66-81  sO = v82-97  wO = v98-113
//   ring: 8 slots x 8 dwords (16 halves = 1 step) = v114-v177,
//   16 loads in flight, wait vmcnt(14).

#define DCELL2(aS,aA,aB,aC,aQ,aH,aW, bS,bA,bB,bC,bQ,bH,bW) \
  "v_min3_f32 v" #aS ", v" #aA ", v" #aB ", v" #aC "\n\t" \
  "v_min3_f32 v" #bS ", v" #bA ", v" #bB ", v" #bC "\n\t" \
  "v_fma_mix_f32 v" #aS ", v" #aQ ", 1.0, v" #aS " op_sel:[" #aH ",0,0] op_sel_hi:[1,0,0]\n\t" \
  "v_fma_mix_f32 v" #bS ", v" #bQ ", 1.0, v" #bS " op_sel:[" #bH ",0,0] op_sel_hi:[1,0,0]\n\t" \
  "v_add_f32 v" #aW ", %[wK], v" #aS "\n\t" \
  "v_add_f32 v" #bW ", %[wK], v" #bS "\n\t"

// STEP_E: reads sE/wE (+tinE,tinWO), writes sO/wO. Dword Qk holds halves 2k,2k+1.
#define STEP_E(Q0,Q1,Q2,Q3,Q4,Q5,Q6,Q7) \
  DCELL2(82, 45, 48, 66, Q0,0, 98,    90, 89, 73, 74, Q4,0, 106) \
  DCELL2(83, 50, 98, 67, Q0,1, 99,    91, 58, 106, 75, Q4,1, 107) \
  DCELL2(84, 51, 99, 68, Q1,0, 100,   92, 59, 107, 76, Q5,0, 108) \
  DCELL2(85, 52, 100, 69, Q1,1, 101,  93, 60, 108, 77, Q5,1, 109) \
  DCELL2(86, 53, 101, 70, Q2,0, 102,  94, 61, 109, 78, Q6,0, 110) \
  DCELL2(87, 54, 102, 71, Q2,1, 103,  95, 62, 110, 79, Q6,1, 111) \
  DCELL2(88, 55, 103, 72, Q3,0, 104,  96, 63, 111, 80, Q7,0, 112) \
  DCELL2(89, 56, 104, 73, Q3,1, 105,  97, 64, 112, 81, Q7,1, 113)

#define STEP_O(Q0,Q1,Q2,Q3,Q4,Q5,Q6,Q7) \
  DCELL2(50, 47, 46, 98, Q0,0, 66,    58, 57, 105, 106, Q4,0, 74) \
  DCELL2(51, 82, 66, 99, Q0,1, 67,    59, 90, 74, 107, Q4,1, 75) \
  DCELL2(52, 83, 67, 100, Q1,0, 68,   60, 91, 75, 108, Q5,0, 76) \
  DCELL2(53, 84, 68, 101, Q1,1, 69,   61, 92, 76, 109, Q5,1, 77) \
  DCELL2(54, 85, 69, 102, Q2,0, 70,   62, 93, 77, 110, Q6,0, 78) \
  DCELL2(55, 86, 70, 103, Q2,1, 71,   63, 94, 78, 111, Q6,1, 79) \
  DCELL2(56, 87, 71, 104, Q3,0, 72,   64, 95, 79, 112, Q7,0, 80) \
  DCELL2(57, 88, 72, 105, Q3,1, 73,   65, 96, 80, 113, Q7,1, 81)

#define HO_E \
  "s_nop 1\n\t" \
  "v_mov_b32_dpp v43, v97 wave_shr:1 row_mask:0xf bank_mask:0xf bound_ctrl:0\n\t" \
  "v_cndmask_b32 v45, v43, v42, %[msk]\n\t" \
  "v_add_f32 v46, %[wK], v45\n\t"

#define HO_O \
  "s_nop 1\n\t" \
  "v_mov_b32_dpp v43, v65 wave_shr:1 row_mask:0xf bank_mask:0xf bound_ctrl:0\n\t" \
  "v_cndmask_b32 v47, v43, v42, %[msk]\n\t" \
  "v_add_f32 v48, %[wK], v47\n\t"

#define PREF(r0,r1,K) \
  "s_add_u32 %[st], %[su], " #K "\n\t" \
  "v_med3_i32 v43, %[st], %[vlo], %[vhi]\n\t" \
  "v_mad_u32_u24 v44, v43, %[c32], %[vl4]\n\t" \
  "global_load_dwordx4 " r0 ", v44, %[bp]\n\t" \
  "global_load_dwordx4 " r1 ", v44, %[bp] offset:16\n\t"

#define PREF0(K) PREF("v[114:117]","v[118:121]",K)
#define PREF1(K) PREF("v[122:125]","v[126:129]",K)
#define PREF2(K) PREF("v[130:133]","v[134:137]",K)
#define PREF3(K) PREF("v[138:141]","v[142:145]",K)
#define PREF4(K) PREF("v[146:149]","v[150:153]",K)
#define PREF5(K) PREF("v[154:157]","v[158:161]",K)
#define PREF6(K) PREF("v[162:165]","v[166:169]",K)
#define PREF7(K) PREF("v[170:173]","v[174:177]",K)

#define SLOT0 (114,115,116,117,118,119,120,121)
#define SLOT1 (122,123,124,125,126,127,128,129)
#define SLOT2 (130,131,132,133,134,135,136,137)
#define SLOT3 (138,139,140,141,142,143,144,145)
#define SLOT4 (146,147,148,149,150,151,152,153)
#define SLOT5 (154,155,156,157,158,159,160,161)
#define SLOT6 (162,163,164,165,166,167,168,169)
#define SLOT7 (170,171,172,173,174,175,176,177)

// Indirection so `M` is rescanned adjacent to the prescan-expanded paren list.
#define DTW_CALL(M, A) M A

#define MV(n) "v_mov_b32 v" #n ", v42\n\t"
#define W14 "s_waitcnt vmcnt(14)\n\t"

__global__ __launch_bounds__(64)
void dtw_wave_kernel(const _Float16* __restrict__ Dm, float* __restrict__ dtwv) {
    const int kb = blockIdx.x;
    const int l  = threadIdx.x;
    const int lc = l < 49 ? l : 49;             // lanes 50-63 mirror lane 49
    const _Float16* __restrict__ Dd = Dm + (size_t)kb * SLAB_;

    const int ti_l = lc >> 2;
    const int Jlo = ti_l >= 2 ? 64 * (ti_l - 2) : 0;
    const int Jhi = min(799, 64 * ti_l + 191);
    const int lo_u = (Jlo == 0) ? (2 * lc) : (Jlo + 2 * lc + 1);
    const int hi_u = Jhi + 2 * lc + 1;
    const unsigned lofs = (unsigned)(lc << 5);      // 32 B per lane within row

    float res;
    unsigned su_d, st_d;

    asm volatile(
        // ---- init constants & state
        "v_mov_b32 v42, %[vbig]\n\t"
        MV(50) MV(51) MV(52) MV(53) MV(54) MV(55) MV(56) MV(57)
        MV(58) MV(59) MV(60) MV(61) MV(62) MV(63) MV(64) MV(65)
        MV(66) MV(67) MV(68) MV(69) MV(70) MV(71) MV(72) MV(73)
        MV(74) MV(75) MV(76) MV(77) MV(78) MV(79) MV(80) MV(81)
        MV(82) MV(83) MV(84) MV(85) MV(86) MV(87) MV(88) MV(89)
        MV(90) MV(91) MV(92) MV(93) MV(94) MV(95) MV(96) MV(97)
        MV(98) MV(99) MV(100) MV(101) MV(102) MV(103) MV(104) MV(105)
        MV(106) MV(107) MV(108) MV(109) MV(110) MV(111) MV(112) MV(113)
        "v_cndmask_b32 v45, v42, 0, %[msk]\n\t"   // tinE: lane0 -> 0, else BIG
        "v_mov_b32 v46, v42\n\t"                  // tinWE
        "v_mov_b32 v47, v42\n\t"                  // tinO
        "v_mov_b32 v48, v42\n\t"                  // tinWO (read at step 0: BIG)
        "s_mov_b32 %[su], 0\n\t"
        // ---- prefill 8 slots (u = 0..7), 16 loads in flight
        PREF0(0) PREF1(1) PREF2(2) PREF3(3) PREF4(4) PREF5(5) PREF6(6) PREF7(7)
        // ---- main loop: 111 iters x 8 steps = steps 0..887
        "1:\n\t"
        W14 DTW_CALL(STEP_E, SLOT0) HO_E PREF0(8)
        W14 DTW_CALL(STEP_O, SLOT1) HO_O PREF1(9)
        W14 DTW_CALL(STEP_E, SLOT2) HO_E PREF2(10)
        W14 DTW_CALL(STEP_O, SLOT3) HO_O PREF3(11)
        W14 DTW_CALL(STEP_E, SLOT4) HO_E PREF4(12)
        W14 DTW_CALL(STEP_O, SLOT5) HO_O PREF5(13)
        W14 DTW_CALL(STEP_E, SLOT6) HO_E PREF6(14)
        W14 DTW_CALL(STEP_O, SLOT7) HO_O PREF7(15)
        "s_add_u32 %[su], %[su], 8\n\t"
        "s_cmp_lg_u32 %[su], 888\n\t"
        "s_cbranch_scc1 1b\n\t"
        // ---- tail: steps 888..898 (su = 888)
        W14 DTW_CALL(STEP_E, SLOT0) HO_E PREF0(8)            // 888, refill 896
        W14 DTW_CALL(STEP_O, SLOT1) HO_O PREF1(9)            // 889, refill 897
        W14 DTW_CALL(STEP_E, SLOT2) HO_E PREF2(10)           // 890, refill 898
        W14 DTW_CALL(STEP_O, SLOT3) HO_O                     // 891
        "s_waitcnt vmcnt(12)\n\t" DTW_CALL(STEP_E, SLOT4) HO_E   // 892
        "s_waitcnt vmcnt(10)\n\t" DTW_CALL(STEP_O, SLOT5) HO_O   // 893
        "s_waitcnt vmcnt(8)\n\t"  DTW_CALL(STEP_E, SLOT6) HO_E   // 894
        "s_waitcnt vmcnt(6)\n\t"  DTW_CALL(STEP_O, SLOT7) HO_O   // 895
        "s_waitcnt vmcnt(4)\n\t"  DTW_CALL(STEP_E, SLOT0) HO_E   // 896
        "s_waitcnt vmcnt(2)\n\t"  DTW_CALL(STEP_O, SLOT1) HO_O   // 897
        "s_waitcnt vmcnt(0)\n\t"  DTW_CALL(STEP_E, SLOT2)        // 898
        "v_mov_b32 %[res], v97\n\t"
        : [res] "=v"(res), [su] "=&s"(su_d), [st] "=&s"(st_d)
        : [vlo] "v"(lo_u), [vhi] "v"(hi_u), [vl4] "v"(lofs),
          [vbig] "v"(BIGV), [wK] "s"(WARP_V), [c32] "s"(1600u),
          [msk] "s"(1ull), [bp] "s"((const void*)Dd)
        : "memory", "scc",
          "v42","v43","v44","v45","v46","v47","v48","v49",
          "v50","v51","v52","v53","v54","v55","v56","v57","v58","v59",
          "v60","v61","v62","v63","v64","v65","v66","v67","v68","v69",
          "v70","v71","v72","v73","v74","v75","v76","v77","v78","v79",
          "v80","v81","v82","v83","v84","v85","v86","v87","v88","v89",
          "v90","v91","v92","v93","v94","v95","v96","v97","v98","v99",
          "v100","v101","v102","v103","v104","v105","v106","v107","v108","v109",
          "v110","v111","v112","v113","v114","v115","v116","v117","v118","v119",
          "v120","v121","v122","v123","v124","v125","v126","v127","v128","v129",
          "v130","v131","v132","v133","v134","v135","v136","v137","v138","v139",
          "v140","v141","v142","v143","v144","v145","v146","v147","v148","v149",
          "v150","v151","v152","v153","v154","v155","v156","v157","v158","v159",
          "v160","v161","v162","v163","v164","v165","v166","v167","v168","v169",
          "v170","v171","v172","v173","v174","v175","v176","v177"
    );

    if (l == 49) dtwv[kb] = res;
}

// ---------------------------------------------------------------- finalize (scalars)
__global__ void finalize_kernel(const float* __restrict__ dtwv, const int* __restrict__ mel_lens,
                                const int* __restrict__ src_lens, const float* __restrict__ durations,
                                const float* __restrict__ mus, const float* __restrict__ log_vars,
                                const int* __restrict__ step, float* __restrict__ out) {
    const int lane = threadIdx.x;  // 64 threads, one wave

    float v = (lane < KB_) ? dtwv[lane] : 0.f;
    for (int o = 32; o; o >>= 1) v += __shfl_down(v, o);

    float w = (lane < B_) ? 1.f / (K_ * (float)mel_lens[lane]) : 0.f;
    for (int o = 32; o; o >>= 1) w += __shfl_down(w, o);

    float du = 0.f;
    if (lane < B_) {
        float s = 0.f;
        for (int j = 0; j < S_; ++j) s += durations[lane * S_ + j];
        du = fabsf(s - (float)mel_lens[lane]) / (float)src_lens[lane];
    }
    for (int o = 32; o; o >>= 1) du += __shfl_down(du, o);

    float kl = 0.f;
    for (int j = lane; j < B_ * Z_; j += 64) {
        float muv = mus[j], lv = log_vars[j];
        kl += 1.f + lv - muv * muv - expf(lv);
    }
    for (int o = 32; o; o >>= 1) kl += __shfl_down(kl, o);

    if (lane == 0) {
        float mel_iter_loss = v / (float)B_;
        float mel_loss = mel_iter_loss * (w / (float)B_);
        float dur_loss = 2.0f * du / (float)B_;
        float kl_loss = -0.5f * kl;
        int st = step[0];
        float beta = (st < 2000) ? 0.f : ((st >= 8000) ? 1.f : (float)(st - 2000) / 6000.f);
        out[0] = mel_loss + dur_loss + beta * kl_loss;
        out[1] = mel_loss;
        out[2] = dur_loss;
        out[3] = kl_loss;
        out[4] = beta;
    }
}

// ---------------------------------------------------------------- launch
extern "C" void kernel_launch(void* const* d_in, const int* in_sizes, int n_in,
                              void* d_out, int out_size, void* d_ws, size_t ws_size,
                              hipStream_t stream) {
    const float* mel_iters   = (const float*)d_in[0];
    const float* mel_targets = (const float*)d_in[1];
    const int*   mel_lens    = (const int*)d_in[2];
    const int*   src_lens    = (const int*)d_in[3];
    const float* durations   = (const float*)d_in[4];
    const float* mus         = (const float*)d_in[5];
    const float* log_vars    = (const float*)d_in[6];
    const int*   step        = (const int*)d_in[7];
    float* out = (float*)d_out;

    _Float16* Dm = (_Float16*)d_ws;                               // 32 * 720,000 halves = 46 MB
    float* dtwv  = (float*)((char*)d_ws + (size_t)KB_ * SLAB_ * sizeof(_Float16));

    gemm_band<<<dim3(5, 13, KB_), 256, 0, stream>>>(mel_iters, mel_targets, Dm);

    dtw_wave_kernel<<<KB_, 64, 0, stream>>>(Dm, dtwv);

    finalize_kernel<<<1, 64, 0, stream>>>(dtwv, mel_lens, src_lens, durations, mus, log_vars, step, out);
}